// Round 8
// baseline (23.986 us; speedup 1.0000x reference)
//
#include <hip/hip_runtime.h>
#include <hip/hip_bf16.h>

// out[b] = Q[b] @ (K[b]^T @ V[b]) / 8      (softmax in ref is dead code)
// B=8, S=2048, D=128, fp32 in/out. bf16 MFMA, 2 kernels, NO sync primitives
// (device-scope fences/atomics are poison on 8-XCD gfx950: R4/R6 evidence).
//  K1: P[b][ch] (bf16) = K_chunk^T @ V_chunk, CH=8 chunks of 256 rows,
//      d-half split -> 128 blocks x 512 thr. K/V staged via LDS with
//      transpose-on-write (bf16 [d][s], XOR-swizzled) -> ds_read_b128 frags.
//  K2: per-block re-reduce of the batch's 8 partials (L2-hot) -> swizzled
//      transposed LDS M -> Q @ M (64 rows/block, 256 blocks). [R7 verbatim]

#define B 8
#define S 2048
#define D 128
#define CH 8           // s-chunks per batch
#define SC 256         // rows per chunk
#define STG 64         // rows staged per iteration

typedef __attribute__((ext_vector_type(8))) short short8;
typedef __attribute__((ext_vector_type(4))) float f32x4;

static __device__ __forceinline__ short f2bf(float f) {
    __hip_bfloat16 h = __float2bfloat16(f);      // RNE
    union { __hip_bfloat16 h; short s; } u; u.h = h;
    return u.s;
}
static __device__ __forceinline__ float bf2f(unsigned short s) {
    union { unsigned u; float f; } x; x.u = ((unsigned)s) << 16;
    return x.f;
}
static __device__ __forceinline__ int swz(int d, int byte) {
    return byte ^ (((d >> 2) & 7) << 4);         // 16B-granular XOR swizzle
}

// ---- K1: P[b][ch] (bf16) = K_chunk^T @ V_chunk -----------------------------
__global__ __launch_bounds__(512) void k1_ktv(
    const float* __restrict__ K, const float* __restrict__ V,
    unsigned short* __restrict__ P)
{
    int blk = blockIdx.x;                     // 128 = B x 8ch x 2h
    int b = blk >> 4;
    int ch = (blk >> 1) & 7;
    int h  = blk & 1;                         // d-half of the 128x128 output
    const float* Kb = K + ((size_t)b * S + (size_t)ch * SC) * D + h * 64;
    const float* Vb = V + ((size_t)b * S + (size_t)ch * SC) * D;

    // transposed bf16 tiles: [d][64 s], row stride 64 halves = 128 B
    __shared__ unsigned short Kt[64 * STG];   // 8 KB
    __shared__ unsigned short Vt[128 * STG];  // 16 KB

    int tid = threadIdx.x;
    int w = tid >> 6, l = tid & 63;
    int lr = l & 15, lg = l >> 4;
    int ds0 = (w & 3) * 16;                   // a-strip (d within the half)
    int cc0 = (w >> 2) * 64;                  // c-half

    // staging lane maps (coalesced float4 row loads)
    int kd0 = 4 * (tid & 15), ks0 = 2 * (tid >> 4);   // K micro 2s x 4d
    int vd0 = 4 * (tid & 31), vs0 = 4 * (tid >> 5);   // V micro 4s x 4d

    f32x4 acc[4];
#pragma unroll
    for (int j = 0; j < 4; ++j) acc[j] = (f32x4)0.f;

    char* ktb = (char*)Kt;
    char* vtb = (char*)Vt;

#pragma unroll
    for (int st = 0; st < SC / STG; ++st) {
        // ---- global loads (issued before barrier: overlaps prev compute) --
        f32x4 kv[2], vv[4];
        const float* Kg = Kb + (size_t)(st * STG) * D;
        const float* Vg = Vb + (size_t)(st * STG) * D;
#pragma unroll
        for (int r = 0; r < 2; ++r)
            kv[r] = *(const f32x4*)(Kg + (size_t)(ks0 + r) * D + kd0);
#pragma unroll
        for (int r = 0; r < 4; ++r)
            vv[r] = *(const f32x4*)(Vg + (size_t)(vs0 + r) * D + vd0);

        if (st > 0) __syncthreads();          // prev stage's reads complete

        // ---- transpose-on-write to LDS (bf16) -----------------------------
#pragma unroll
        for (int j = 0; j < 4; ++j) {         // K: pair (ks0, ks0+1) per d
            int d = kd0 + j;
            unsigned pv = (unsigned)(unsigned short)f2bf(kv[0][j]) |
                          ((unsigned)(unsigned short)f2bf(kv[1][j]) << 16);
            *(unsigned*)(ktb + swz(d, (d << 7) + (ks0 << 1))) = pv;
        }
#pragma unroll
        for (int j = 0; j < 4; ++j) {         // V: quad (vs0..vs0+3) per d
            int d = vd0 + j;
            uint2 qv;
            qv.x = (unsigned)(unsigned short)f2bf(vv[0][j]) |
                   ((unsigned)(unsigned short)f2bf(vv[1][j]) << 16);
            qv.y = (unsigned)(unsigned short)f2bf(vv[2][j]) |
                   ((unsigned)(unsigned short)f2bf(vv[3][j]) << 16);
            *(uint2*)(vtb + swz(d, (d << 7) + (vs0 << 1))) = qv;
        }
        __syncthreads();

        // ---- fragments (ds_read_b128) + MFMA ------------------------------
#pragma unroll
        for (int ks = 0; ks < 2; ++ks) {
            int sb = ks * 32 + lg * 8;        // this lane's 8 s-elems
            int da = ds0 + lr;
            short8 af = *(const short8*)(ktb + swz(da, (da << 7) + (sb << 1)));
#pragma unroll
            for (int fj = 0; fj < 4; ++fj) {
                int c = cc0 + fj * 16 + lr;
                short8 bv = *(const short8*)(vtb + swz(c, (c << 7) + (sb << 1)));
                acc[fj] = __builtin_amdgcn_mfma_f32_16x16x32_bf16(
                    af, bv, acc[fj], 0, 0, 0);
            }
        }
    }

    unsigned short* Pb = P + (size_t)(b * CH + ch) * D * D;
#pragma unroll
    for (int fj = 0; fj < 4; ++fj)
#pragma unroll
        for (int j = 0; j < 4; ++j) {
            int row = h * 64 + ds0 + lg * 4 + j;
            int col = cc0 + fj * 16 + lr;
            Pb[row * D + col] = (unsigned short)f2bf(acc[fj][j]);
        }
}

// ---- K2: re-reduce partials -> LDS M^T (swizzled) -> out = Q @ M -----------
__global__ __launch_bounds__(256) void k2_rqm(
    const float* __restrict__ Q, const unsigned short* __restrict__ P,
    float* __restrict__ Out)
{
    __shared__ unsigned short MT[D * D];       // 32 KB, byte-swizzled [c][k]

    int blk = blockIdx.x;                      // 256 = 8b x 32 row-tiles
    int b = blk >> 5, t = blk & 31;
    int tid = threadIdx.x;

    // ---- phase 1: reduce 8 partials; thread owns d0..d0+8 x c0..c0+8 ------
    int cblk = tid & 15, dblk = tid >> 4;
    int c0 = cblk * 8, d0 = dblk * 8;
    const unsigned short* Pb = P + (size_t)(b * CH) * D * D;

    float m[8][8];                             // [j = d-local][i = c-local]
#pragma unroll
    for (int j = 0; j < 8; ++j)
#pragma unroll
        for (int i = 0; i < 8; ++i) m[j][i] = 0.f;

#pragma unroll
    for (int cc = 0; cc < CH; ++cc) {
#pragma unroll
        for (int j = 0; j < 8; ++j) {
            short8 pv = *(const short8*)(Pb + (size_t)cc * D * D + (d0 + j) * D + c0);
#pragma unroll
            for (int i = 0; i < 8; ++i)
                m[j][i] += bf2f((unsigned short)pv[i]);
        }
    }

    // ---- phase 2: write M^T (x 1/8) to LDS, swizzled -----------------------
    char* mt = (char*)MT;
#pragma unroll
    for (int i = 0; i < 8; ++i) {
        int c = c0 + i;
        short8 sv;
#pragma unroll
        for (int j = 0; j < 8; ++j) sv[j] = f2bf(m[j][i] * 0.125f);
        int X = ((c & 7) ^ (cblk & 7)) & 7;    // cblk == c>>3 here
        int byte = (c * 256 + 2 * d0) ^ (X << 4);
        *(short8*)(mt + byte) = sv;
    }
    __syncthreads();

    // ---- phase 3: out rows r0..r0+16 per wave = Q @ M ----------------------
    int w = tid >> 6, l = tid & 63;
    int lr = l & 15, lg = l >> 4;
    int r0 = t * 64 + w * 16;

    const float* Qb = Q + ((size_t)b * S + r0) * D;

    f32x4 acc[8];
#pragma unroll
    for (int j = 0; j < 8; ++j) acc[j] = (f32x4)0.f;

#pragma unroll
    for (int ks = 0; ks < 4; ++ks) {
        int k0 = ks * 32 + lg * 8;
        const float* qp = Qb + (size_t)lr * D + k0;
        float4 q0 = *(const float4*)qp;
        float4 q1 = *(const float4*)(qp + 4);
        short8 a;
        a[0] = f2bf(q0.x); a[1] = f2bf(q0.y); a[2] = f2bf(q0.z); a[3] = f2bf(q0.w);
        a[4] = f2bf(q1.x); a[5] = f2bf(q1.y); a[6] = f2bf(q1.z); a[7] = f2bf(q1.w);
#pragma unroll
        for (int fj = 0; fj < 8; ++fj) {
            int c = fj * 16 + lr;
            int X = ((c & 7) ^ ((c >> 3) & 7)) & 7;
            int byte = (c * 256 + 2 * k0) ^ (X << 4);
            short8 bb = *(const short8*)(mt + byte);
            acc[fj] = __builtin_amdgcn_mfma_f32_16x16x32_bf16(a, bb, acc[fj], 0, 0, 0);
        }
    }

    float* Ob = Out + ((size_t)b * S + r0) * D;
#pragma unroll
    for (int fj = 0; fj < 8; ++fj)
#pragma unroll
        for (int j = 0; j < 4; ++j)
            Ob[(size_t)(lg * 4 + j) * D + fj * 16 + lr] = acc[fj][j];
}

extern "C" void kernel_launch(void* const* d_in, const int* in_sizes, int n_in,
                              void* d_out, int out_size, void* d_ws, size_t ws_size,
                              hipStream_t stream)
{
    const float* q = (const float*)d_in[0];
    const float* k = (const float*)d_in[1];
    const float* v = (const float*)d_in[2];
    float* out = (float*)d_out;

    unsigned short* P = (unsigned short*)d_ws;         // 2 MB bf16 partials

    k1_ktv<<<B * CH * 2, 512, 0, stream>>>(k, v, P);
    k2_rqm<<<B * 32, 256, 0, stream>>>(q, P, out);
}

// Round 9
// 22.740 us; speedup vs baseline: 1.0548x; 1.0548x over previous
//
#include <hip/hip_runtime.h>
#include <hip/hip_bf16.h>

// out[b] = Q[b] @ (K[b]^T @ V[b]) / 8      (softmax in ref is dead code)
// B=8, S=2048, D=128, fp32 in/out. bf16 MFMA, 2 kernels, NO sync primitives
// (device-scope fences/atomics are poison on 8-XCD gfx950: R4/R6 evidence).
//  K1: P[b][ch] (bf16) = K_chunk^T @ V_chunk, CH=8 chunks of 256 rows,
//      QUADRANT split (hd,hc) -> 256 blocks x 256 thr (all CUs active).
//      K/V staged via LDS transpose-on-write (bf16 [d][s], XOR-swizzled).
//  K2: per-block re-reduce of the batch's 8 partials (L2-hot) -> swizzled
//      transposed LDS M -> Q @ M (64 rows/block, 256 blocks). [R7 verbatim]

#define B 8
#define S 2048
#define D 128
#define CH 8           // s-chunks per batch
#define SC 256         // rows per chunk
#define STG 64         // rows staged per iteration

typedef __attribute__((ext_vector_type(8))) short short8;
typedef __attribute__((ext_vector_type(4))) float f32x4;

static __device__ __forceinline__ short f2bf(float f) {
    __hip_bfloat16 h = __float2bfloat16(f);      // RNE
    union { __hip_bfloat16 h; short s; } u; u.h = h;
    return u.s;
}
static __device__ __forceinline__ float bf2f(unsigned short s) {
    union { unsigned u; float f; } x; x.u = ((unsigned)s) << 16;
    return x.f;
}
static __device__ __forceinline__ int swz(int d, int byte) {
    return byte ^ (((d >> 2) & 7) << 4);         // 16B-granular XOR swizzle
}
static __device__ __forceinline__ unsigned pack2(float a, float b) {
    return (unsigned)(unsigned short)f2bf(a) |
           ((unsigned)(unsigned short)f2bf(b) << 16);
}

// ---- K1: P[b][ch] (bf16) = K_chunk^T @ V_chunk, quadrant per block ---------
__global__ __launch_bounds__(256) void k1_ktv(
    const float* __restrict__ K, const float* __restrict__ V,
    unsigned short* __restrict__ P)
{
    int blk = blockIdx.x;                     // 256 = b(8) x ch(8) x hd(2) x hc(2)
    int b = blk >> 5, rem = blk & 31;
    int ch = rem >> 2, hd = (rem >> 1) & 1, hc = rem & 1;
    const float* Kb = K + ((size_t)b * S + (size_t)ch * SC) * D + hd * 64;
    const float* Vb = V + ((size_t)b * S + (size_t)ch * SC) * D + hc * 64;

    // transposed bf16 tiles: [d][64 s], row stride 64 halves = 128 B
    __shared__ unsigned short Kt[64 * STG];   // 8 KB
    __shared__ unsigned short Vt[64 * STG];   // 8 KB

    int tid = threadIdx.x;
    int w = tid >> 6, l = tid & 63;
    int lr = l & 15, lg = l >> 4;
    int ds0 = w * 16;                         // wave's d-strip within quadrant

    // staging lane map: rows {rs0, rs0+1, rs0+32, rs0+33}, cols cd0..cd0+3
    int cd0 = 4 * (tid & 15);
    int rs0 = 2 * (tid >> 4);

    f32x4 acc[4];
#pragma unroll
    for (int j = 0; j < 4; ++j) acc[j] = (f32x4)0.f;

    char* ktb = (char*)Kt;
    char* vtb = (char*)Vt;

#pragma unroll
    for (int st = 0; st < SC / STG; ++st) {
        const float* Kg = Kb + (size_t)(st * STG) * D;
        const float* Vg = Vb + (size_t)(st * STG) * D;
        f32x4 kv[4], vv[4];
        kv[0] = *(const f32x4*)(Kg + (size_t)rs0 * D + cd0);
        kv[1] = *(const f32x4*)(Kg + (size_t)(rs0 + 1) * D + cd0);
        kv[2] = *(const f32x4*)(Kg + (size_t)(rs0 + 32) * D + cd0);
        kv[3] = *(const f32x4*)(Kg + (size_t)(rs0 + 33) * D + cd0);
        vv[0] = *(const f32x4*)(Vg + (size_t)rs0 * D + cd0);
        vv[1] = *(const f32x4*)(Vg + (size_t)(rs0 + 1) * D + cd0);
        vv[2] = *(const f32x4*)(Vg + (size_t)(rs0 + 32) * D + cd0);
        vv[3] = *(const f32x4*)(Vg + (size_t)(rs0 + 33) * D + cd0);

        if (st > 0) __syncthreads();          // prev stage's reads complete

        // transpose-on-write to LDS (bf16 pairs)
#pragma unroll
        for (int j = 0; j < 4; ++j) {
            int d = cd0 + j;
            *(unsigned*)(ktb + swz(d, (d << 7) + (rs0 << 1))) =
                pack2(kv[0][j], kv[1][j]);
            *(unsigned*)(ktb + swz(d, (d << 7) + ((rs0 + 32) << 1))) =
                pack2(kv[2][j], kv[3][j]);
            *(unsigned*)(vtb + swz(d, (d << 7) + (rs0 << 1))) =
                pack2(vv[0][j], vv[1][j]);
            *(unsigned*)(vtb + swz(d, (d << 7) + ((rs0 + 32) << 1))) =
                pack2(vv[2][j], vv[3][j]);
        }
        __syncthreads();

        // fragments (ds_read_b128) + MFMA
#pragma unroll
        for (int ks = 0; ks < 2; ++ks) {
            int sb = ks * 32 + lg * 8;        // this lane's 8 s-elems
            int da = ds0 + lr;
            short8 af = *(const short8*)(ktb + swz(da, (da << 7) + (sb << 1)));
#pragma unroll
            for (int fj = 0; fj < 4; ++fj) {
                int c = fj * 16 + lr;
                short8 bv = *(const short8*)(vtb + swz(c, (c << 7) + (sb << 1)));
                acc[fj] = __builtin_amdgcn_mfma_f32_16x16x32_bf16(
                    af, bv, acc[fj], 0, 0, 0);
            }
        }
    }

    unsigned short* Pb = P + (size_t)(b * CH + ch) * D * D;
#pragma unroll
    for (int fj = 0; fj < 4; ++fj)
#pragma unroll
        for (int j = 0; j < 4; ++j) {
            int row = hd * 64 + ds0 + lg * 4 + j;
            int col = hc * 64 + fj * 16 + lr;
            Pb[row * D + col] = (unsigned short)f2bf(acc[fj][j]);
        }
}

// ---- K2: re-reduce partials -> LDS M^T (swizzled) -> out = Q @ M -----------
__global__ __launch_bounds__(256) void k2_rqm(
    const float* __restrict__ Q, const unsigned short* __restrict__ P,
    float* __restrict__ Out)
{
    __shared__ unsigned short MT[D * D];       // 32 KB, byte-swizzled [c][k]

    int blk = blockIdx.x;                      // 256 = 8b x 32 row-tiles
    int b = blk >> 5, t = blk & 31;
    int tid = threadIdx.x;

    // ---- phase 1: reduce 8 partials; thread owns d0..d0+8 x c0..c0+8 ------
    int cblk = tid & 15, dblk = tid >> 4;
    int c0 = cblk * 8, d0 = dblk * 8;
    const unsigned short* Pb = P + (size_t)(b * CH) * D * D;

    float m[8][8];                             // [j = d-local][i = c-local]
#pragma unroll
    for (int j = 0; j < 8; ++j)
#pragma unroll
        for (int i = 0; i < 8; ++i) m[j][i] = 0.f;

#pragma unroll
    for (int cc = 0; cc < CH; ++cc) {
#pragma unroll
        for (int j = 0; j < 8; ++j) {
            short8 pv = *(const short8*)(Pb + (size_t)cc * D * D + (d0 + j) * D + c0);
#pragma unroll
            for (int i = 0; i < 8; ++i)
                m[j][i] += bf2f((unsigned short)pv[i]);
        }
    }

    // ---- phase 2: write M^T (x 1/8) to LDS, swizzled -----------------------
    char* mt = (char*)MT;
#pragma unroll
    for (int i = 0; i < 8; ++i) {
        int c = c0 + i;
        short8 sv;
#pragma unroll
        for (int j = 0; j < 8; ++j) sv[j] = f2bf(m[j][i] * 0.125f);
        int X = ((c & 7) ^ (cblk & 7)) & 7;    // cblk == c>>3 here
        int byte = (c * 256 + 2 * d0) ^ (X << 4);
        *(short8*)(mt + byte) = sv;
    }
    __syncthreads();

    // ---- phase 3: out rows r0..r0+16 per wave = Q @ M ----------------------
    int w = tid >> 6, l = tid & 63;
    int lr = l & 15, lg = l >> 4;
    int r0 = t * 64 + w * 16;

    const float* Qb = Q + ((size_t)b * S + r0) * D;

    f32x4 acc[8];
#pragma unroll
    for (int j = 0; j < 8; ++j) acc[j] = (f32x4)0.f;

#pragma unroll
    for (int ks = 0; ks < 4; ++ks) {
        int k0 = ks * 32 + lg * 8;
        const float* qp = Qb + (size_t)lr * D + k0;
        float4 q0 = *(const float4*)qp;
        float4 q1 = *(const float4*)(qp + 4);
        short8 a;
        a[0] = f2bf(q0.x); a[1] = f2bf(q0.y); a[2] = f2bf(q0.z); a[3] = f2bf(q0.w);
        a[4] = f2bf(q1.x); a[5] = f2bf(q1.y); a[6] = f2bf(q1.z); a[7] = f2bf(q1.w);
#pragma unroll
        for (int fj = 0; fj < 8; ++fj) {
            int c = fj * 16 + lr;
            int X = ((c & 7) ^ ((c >> 3) & 7)) & 7;
            int byte = (c * 256 + 2 * k0) ^ (X << 4);
            short8 bb = *(const short8*)(mt + byte);
            acc[fj] = __builtin_amdgcn_mfma_f32_16x16x32_bf16(a, bb, acc[fj], 0, 0, 0);
        }
    }

    float* Ob = Out + ((size_t)b * S + r0) * D;
#pragma unroll
    for (int fj = 0; fj < 8; ++fj)
#pragma unroll
        for (int j = 0; j < 4; ++j)
            Ob[(size_t)(lg * 4 + j) * D + fj * 16 + lr] = acc[fj][j];
}

extern "C" void kernel_launch(void* const* d_in, const int* in_sizes, int n_in,
                              void* d_out, int out_size, void* d_ws, size_t ws_size,
                              hipStream_t stream)
{
    const float* q = (const float*)d_in[0];
    const float* k = (const float*)d_in[1];
    const float* v = (const float*)d_in[2];
    float* out = (float*)d_out;

    unsigned short* P = (unsigned short*)d_ws;         // 2 MB bf16 partials

    k1_ktv<<<B * CH * 2 * 2, 256, 0, stream>>>(k, v, P);
    k2_rqm<<<B * 32, 256, 0, stream>>>(q, P, out);
}